// Round 5
// baseline (370.089 us; speedup 1.0000x reference)
//
#include <hip/hip_runtime.h>
#include <cstdio>
#include <cstdint>

// GridSelfAttention: N=320 seq, C=128 ch, H=4 heads, D=32 head-dim.
// k0 prep -> k1 LN+proj GEMM (128-row blocks) -> k2 attention (S^T/wa^T
// orientation, online softmax, scalar-per-lane state) -> k3 output GEMM.

#define NSEQ 320
#define CCH  128
#define NN   102400
#define QK_SCALE 0.17677669529663687f
#define LN_EPS 1e-5f
#define NEG_BIG -1e9f

typedef __bf16 bf16x8 __attribute__((ext_vector_type(8)));
typedef float  f32x4  __attribute__((ext_vector_type(4)));

__device__ __forceinline__ unsigned short f2bf(float f) {
    unsigned int u = __float_as_uint(f);
    unsigned int r = (u + 0x7FFFu + ((u >> 16) & 1u)) >> 16;  // RNE
    return (unsigned short)r;
}
__device__ __forceinline__ float bf2f(unsigned short h) {
    return __uint_as_float(((unsigned int)h) << 16);
}

// ---------------- k0: weight prep + mask transpose ----------------
// blocks [0,352): wcat/woutb; blocks [352,377): 64x64 LDS-tiled maskT transpose.
__global__ __launch_bounds__(256) void prep_kernel(
    const float* __restrict__ wq, const float* __restrict__ wk, const float* __restrict__ wv,
    const float* __restrict__ wg, const float* __restrict__ wpb, const float* __restrict__ wo,
    const int* __restrict__ pmask,
    unsigned short* __restrict__ wcat, unsigned short* __restrict__ woutb, int* __restrict__ maskT)
{
    const int tid = threadIdx.x;
    if (blockIdx.x < 352) {
        int idx = blockIdx.x * 256 + tid;
        if (idx < 576 * 128) {
            int n = idx >> 7, c = idx & 127;
            float v;
            if      (n < 128) v = wq[c * 128 + n] * QK_SCALE;
            else if (n < 256) v = wk[c * 128 + (n - 128)];
            else if (n < 384) v = wv[c * 128 + (n - 256)];
            else if (n < 512) v = wg[c * 128 + (n - 384)];
            else if (n < 516) v = wpb[c * 4 + (n - 512)];
            else              v = 0.f;
            wcat[idx] = f2bf(v);
        } else {
            int i = idx - 576 * 128;
            woutb[i] = f2bf(wo[i]);
        }
    } else {
        __shared__ int tile[64][65];
        int tb = blockIdx.x - 352;
        int ti = tb / 5, tj = tb % 5;     // maskT[b][k]=pmask[k][b]; read rows k=ti*64.., cols b=tj*64..
        #pragma unroll
        for (int it = 0; it < 16; ++it) {
            int e = it * 256 + tid;
            int r = e >> 6, c = e & 63;
            tile[r][c] = pmask[(ti * 64 + r) * NSEQ + tj * 64 + c];
        }
        __syncthreads();
        #pragma unroll
        for (int it = 0; it < 16; ++it) {
            int e = it * 256 + tid;
            int r = e >> 6, c = e & 63;
            maskT[(tj * 64 + r) * NSEQ + ti * 64 + c] = tile[c][r];
        }
    }
}

// ---------------- k1: LayerNorm + fused projection GEMM ----------------
// 128 rows/block. Outputs: qh/kh/gh[(g)*320+pos][32] bf16, vT[(g)*32+d][key] bf16,
// biasS in k2's S^T C-fragment order.
__global__ __launch_bounds__(256, 3) void ln_proj_kernel(
    const float* __restrict__ act, const float* __restrict__ gamma, const float* __restrict__ beta,
    const unsigned short* __restrict__ wcat,
    unsigned short* __restrict__ qh, unsigned short* __restrict__ kh, unsigned short* __restrict__ vT,
    unsigned short* __restrict__ gh, float* __restrict__ biasS)
{
    __shared__ __align__(16) unsigned short A_lds[128 * 138];   // 35328 B; later fp32 scratch 128x69
    __shared__ __align__(16) unsigned short B_lds[64 * 138];    // 17664 B

    const int tid  = threadIdx.x;
    const int row0 = blockIdx.x * 128;
    const int wave = tid >> 6, lane = tid & 63, l15 = lane & 15, l4 = lane >> 4;

    // LN: 4 threads/row, direct from global, 2 passes of 64 rows
    #pragma unroll
    for (int p = 0; p < 2; ++p) {
        int row = p * 64 + (tid >> 2), seg = tid & 3;
        const float* rp = act + (size_t)(row0 + row) * 128 + seg * 32;
        float vals[32];
        float s = 0.f, sq = 0.f;
        #pragma unroll
        for (int i = 0; i < 8; ++i) {
            float4 v = *(const float4*)&rp[i * 4];
            vals[i*4+0]=v.x; vals[i*4+1]=v.y; vals[i*4+2]=v.z; vals[i*4+3]=v.w;
            s += v.x+v.y+v.z+v.w; sq += v.x*v.x+v.y*v.y+v.z*v.z+v.w*v.w;
        }
        s  += __shfl_xor(s, 1);  sq += __shfl_xor(sq, 1);
        s  += __shfl_xor(s, 2);  sq += __shfl_xor(sq, 2);
        float mean = s * (1.f / 128.f);
        float var  = sq * (1.f / 128.f) - mean * mean;
        float rstd = rsqrtf(var + LN_EPS);
        #pragma unroll
        for (int j = 0; j < 4; ++j) {
            int c0 = seg * 32 + j * 8;
            float4 g0 = *(const float4*)&gamma[c0];
            float4 g1 = *(const float4*)&gamma[c0 + 4];
            float4 b0 = *(const float4*)&beta[c0];
            float4 b1 = *(const float4*)&beta[c0 + 4];
            union { uint4 u; unsigned short us[8]; } pk;
            pk.us[0] = f2bf((vals[j*8+0] - mean) * rstd * g0.x + b0.x);
            pk.us[1] = f2bf((vals[j*8+1] - mean) * rstd * g0.y + b0.y);
            pk.us[2] = f2bf((vals[j*8+2] - mean) * rstd * g0.z + b0.z);
            pk.us[3] = f2bf((vals[j*8+3] - mean) * rstd * g0.w + b0.w);
            pk.us[4] = f2bf((vals[j*8+4] - mean) * rstd * g1.x + b1.x);
            pk.us[5] = f2bf((vals[j*8+5] - mean) * rstd * g1.y + b1.y);
            pk.us[6] = f2bf((vals[j*8+6] - mean) * rstd * g1.z + b1.z);
            pk.us[7] = f2bf((vals[j*8+7] - mean) * rstd * g1.w + b1.w);
            *(uint4*)&A_lds[row * 138 + c0] = pk.u;
        }
    }
    __syncthreads();

    // A fragments: wave handles rows wave*16.. (tile0) and 64+wave*16.. (tile1)
    bf16x8 afrag[2][4];
    #pragma unroll
    for (int tl = 0; tl < 2; ++tl)
        #pragma unroll
        for (int kc = 0; kc < 4; ++kc)
            afrag[tl][kc] = *(const bf16x8*)&A_lds[(tl * 64 + wave * 16 + l15) * 138 + kc * 32 + l4 * 8];

    float* scratch = (float*)A_lds;   // 128 x 69 fp32 = 35328 B (A_lds free after afrag extraction)

    for (int nt = 0; nt < 9; ++nt) {
        #pragma unroll
        for (int it = 0; it < 4; ++it) {
            int f = it * 256 + tid;
            int row = f >> 4, c16 = f & 15;
            uint4 u = *(const uint4*)&wcat[(nt * 64 + row) * 128 + c16 * 8];
            *(uint4*)&B_lds[row * 138 + c16 * 8] = u;
        }
        __syncthreads();

        f32x4 acc[2][4];
        #pragma unroll
        for (int tl = 0; tl < 2; ++tl)
            #pragma unroll
            for (int ns = 0; ns < 4; ++ns) { f32x4 z = {0.f,0.f,0.f,0.f}; acc[tl][ns] = z; }
        #pragma unroll
        for (int ns = 0; ns < 4; ++ns)
            #pragma unroll
            for (int kc = 0; kc < 4; ++kc) {
                bf16x8 bfrag = *(const bf16x8*)&B_lds[(ns * 16 + l15) * 138 + kc * 32 + l4 * 8];
                #pragma unroll
                for (int tl = 0; tl < 2; ++tl)
                    acc[tl][ns] = __builtin_amdgcn_mfma_f32_16x16x32_bf16(afrag[tl][kc], bfrag, acc[tl][ns], 0, 0, 0);
            }

        if (nt == 4 || nt == 5) {
            // V -> vT direct from C-frags (4 consecutive keys per lane; 4 | 320 so runs never cross b)
            #pragma unroll
            for (int tl = 0; tl < 2; ++tl) {
                int R = row0 + tl * 64 + wave * 16 + l4 * 4;
                int bb = R / NSEQ, key0 = R - bb * NSEQ;
                #pragma unroll
                for (int ns = 0; ns < 4; ++ns) {
                    int j  = nt * 64 + ns * 16 + l15 - 256;   // 0..127
                    int hh = j >> 5, d = j & 31;
                    ushort4 pk;
                    pk.x = f2bf(acc[tl][ns][0]); pk.y = f2bf(acc[tl][ns][1]);
                    pk.z = f2bf(acc[tl][ns][2]); pk.w = f2bf(acc[tl][ns][3]);
                    *(ushort4*)&vT[((size_t)(bb * 4 + hh) * 32 + d) * NSEQ + key0] = pk;
                }
            }
            __syncthreads();   // protect B_lds before next staging
        } else if (nt == 8) {
            // bias -> S^T C-fragment order: within tile, lane=(keyquad)*16+(q&15), reg=key&3
            if (l15 < 4) {
                int hh = l15;
                #pragma unroll
                for (int tl = 0; tl < 2; ++tl)
                    #pragma unroll
                    for (int reg = 0; reg < 4; ++reg) {
                        int r  = row0 + tl * 64 + wave * 16 + l4 * 4 + reg;
                        int q  = r / NSEQ, key = r - q * NSEQ;
                        size_t a = (((size_t)(hh * 20 + (q >> 4)) * 20 + (key >> 4)) << 8)
                                 + (((key >> 2) & 3) * 16 + (q & 15)) * 4 + (key & 3);
                        biasS[a] = acc[tl][0][reg];   // bias cols live in ns=0, l15=hh
                    }
            }
        } else {
            // q/k/gate: transpose via fp32 scratch (stride 69: odd dword stride, no conflicts)
            #pragma unroll
            for (int tl = 0; tl < 2; ++tl)
                #pragma unroll
                for (int ns = 0; ns < 4; ++ns)
                    #pragma unroll
                    for (int reg = 0; reg < 4; ++reg)
                        scratch[(tl * 64 + wave * 16 + l4 * 4 + reg) * 69 + ns * 16 + l15] = acc[tl][ns][reg];
            __syncthreads();

            int rrow = tid >> 1, half = tid & 1;
            int R = row0 + rrow;
            int bb = R / NSEQ, pos = R - bb * NSEQ;
            float f[32];
            #pragma unroll
            for (int i = 0; i < 8; ++i)
                *(float4*)&f[i * 4] = *(const float4*)&scratch[rrow * 69 + half * 32 + i * 4];

            int jbase = nt * 64 + half * 32;
            int cls   = jbase >> 7;            // 0=q, 1=k, 3=gate
            int hh    = (jbase >> 5) & 3;
            unsigned short* dst = (cls == 0) ? qh : (cls == 1) ? kh : gh;
            if (cls == 3) {
                #pragma unroll
                for (int i = 0; i < 32; ++i) f[i] = 1.f / (1.f + __expf(-f[i]));
            }
            union { uint4 u[4]; unsigned short us[32]; } pk;
            #pragma unroll
            for (int i = 0; i < 32; ++i) pk.us[i] = f2bf(f[i]);
            size_t base = ((size_t)(bb * 4 + hh) * NSEQ + pos) * 32;
            #pragma unroll
            for (int i = 0; i < 4; ++i) *(uint4*)&dst[base + i * 8] = pk.u[i];
        }
    }
}

// ---------------- k2: attention ----------------
// S^T = K*Q^T (row=key, col=q) and wa^T = V^T*P^T (row=d, col=q): softmax state is
// a per-lane scalar (q = lane&15). Online softmax over 2 chunks of 160 keys.
// K in LDS (stride 34), P^T via per-wave LDS dbuf (stride 38), bias as MFMA C.
__global__ __launch_bounds__(256, 5) void attn_kernel(
    const unsigned short* __restrict__ qh, const unsigned short* __restrict__ kh,
    const unsigned short* __restrict__ vT, const unsigned short* __restrict__ gh,
    const float* __restrict__ biasS, const int* __restrict__ maskT,
    unsigned short* __restrict__ waG)
{
    __shared__ __align__(16) unsigned short Klds[320 * 34];     // 21760 B
    __shared__ __align__(16) unsigned short Pb[4][2][16 * 38];  //  9728 B

    const int tid  = threadIdx.x;
    const int bid  = blockIdx.x;
    const int xcd  = bid & 7;
    const int loc  = bid >> 3;
    const int qblk = loc % 5;
    const int g    = (loc / 5) * 8 + xcd;    // (b,h); 5 qblk siblings share an XCD L2
    const int b    = g >> 2;
    const int h    = g & 3;
    const int wave = tid >> 6, lane = tid & 63, l15 = lane & 15, l4 = lane >> 4;

    const size_t hb  = (size_t)g * NSEQ;
    const size_t hbv = (size_t)g * 32;

    // cooperative K staging [key][d], stride 34
    {
        const uint4* src = (const uint4*)(kh + hb * 32);
        #pragma unroll
        for (int it = 0; it < 5; ++it) {
            int idx = it * 256 + tid;
            int key = idx >> 2, part = idx & 3;
            uint4 u = src[idx];
            *(uint4*)&Klds[key * 34 + part * 8] = u;
        }
    }

    const int qrow = qblk * 64 + wave * 16;
    const int qb16 = qblk * 4 + wave;

    bf16x8 bQ = *(const bf16x8*)&qh[(hb + qrow + l15) * 32 + l4 * 8];   // B-frag: n=q
    const float* bsw = biasS + (size_t)(h * 20 + qb16) * 20 * 256 + lane * 4;
    const int4*  mp4 = (const int4*)(maskT + b * NSEQ);

    unsigned short* pb0 = Pb[wave][0];
    unsigned short* pb1 = Pb[wave][1];

    f32x4 acc[2];
    { f32x4 z = {0.f,0.f,0.f,0.f}; acc[0] = z; acc[1] = z; }
    float mrun = -3.4e38f, lrun = 0.f;

    __syncthreads();

    #pragma unroll
    for (int ch = 0; ch < 2; ++ch) {
        const int t0 = ch * 10;
        f32x4 s[10];
        #pragma unroll
        for (int t = 0; t < 10; ++t) s[t] = *(const f32x4*)&bsw[(t0 + t) * 256];
        #pragma unroll
        for (int t = 0; t < 10; ++t) {
            bf16x8 aK = *(const bf16x8*)&Klds[((t0 + t) * 16 + l15) * 34 + l4 * 8];  // A-frag: m=key
            s[t] = __builtin_amdgcn_mfma_f32_16x16x32_bf16(aK, bQ, s[t], 0, 0, 0);
        }
        #pragma unroll
        for (int t = 0; t < 10; ++t) {
            int4 m4 = mp4[(t0 + t) * 4 + l4];     // keys t*16 + quad*4 + {0..3}
            s[t][0] = m4.x ? s[t][0] : NEG_BIG;
            s[t][1] = m4.y ? s[t][1] : NEG_BIG;
            s[t][2] = m4.z ? s[t][2] : NEG_BIG;
            s[t][3] = m4.w ? s[t][3] : NEG_BIG;
        }
        // online softmax partial; state per lane (q = l15)
        float mx = -3.4e38f;
        #pragma unroll
        for (int t = 0; t < 10; ++t)
            #pragma unroll
            for (int r = 0; r < 4; ++r) mx = fmaxf(mx, s[t][r]);
        mx = fmaxf(mx, __shfl_xor(mx, 16));
        mx = fmaxf(mx, __shfl_xor(mx, 32));
        float mnew  = fmaxf(mrun, mx);
        float alpha = __expf(mrun - mnew);
        float l = 0.f;
        #pragma unroll
        for (int t = 0; t < 10; ++t)
            #pragma unroll
            for (int r = 0; r < 4; ++r) { float p = __expf(s[t][r] - mnew); s[t][r] = p; l += p; }
        l += __shfl_xor(l, 16);
        l += __shfl_xor(l, 32);
        lrun = lrun * alpha + l;
        mrun = mnew;
        #pragma unroll
        for (int ns = 0; ns < 2; ++ns)
            #pragma unroll
            for (int r = 0; r < 4; ++r) acc[ns][r] *= alpha;

        // P^T -> Pb[q][key] (ushort4: 4 consecutive keys), dbuf over 32-key sub-chunks
        {
            ushort4 p0, p1;
            p0.x=f2bf(s[0][0]); p0.y=f2bf(s[0][1]); p0.z=f2bf(s[0][2]); p0.w=f2bf(s[0][3]);
            p1.x=f2bf(s[1][0]); p1.y=f2bf(s[1][1]); p1.z=f2bf(s[1][2]); p1.w=f2bf(s[1][3]);
            *(ushort4*)&pb0[l15 * 38 + l4 * 4]      = p0;
            *(ushort4*)&pb0[l15 * 38 + 16 + l4 * 4] = p1;
        }
        #pragma unroll
        for (int kc = 0; kc < 5; ++kc) {
            unsigned short* cur = (kc & 1) ? pb1 : pb0;
            unsigned short* nxt = (kc & 1) ? pb0 : pb1;
            bf16x8 bP = *(const bf16x8*)&cur[l15 * 38 + l4 * 8];   // B-frag: n=q, k=keys
            if (kc < 4) {
                ushort4 p0, p1;
                p0.x=f2bf(s[2*kc+2][0]); p0.y=f2bf(s[2*kc+2][1]); p0.z=f2bf(s[2*kc+2][2]); p0.w=f2bf(s[2*kc+2][3]);
                p1.x=f2bf(s[2*kc+3][0]); p1.y=f2bf(s[2*kc+3][1]); p1.z=f2bf(s[2*kc+3][2]); p1.w=f2bf(s[2*kc+3][3]);
                *(ushort4*)&nxt[l15 * 38 + l4 * 4]      = p0;
                *(ushort4*)&nxt[l15 * 38 + 16 + l4 * 4] = p1;
            }
            #pragma unroll
            for (int ns = 0; ns < 2; ++ns) {
                bf16x8 aV = *(const bf16x8*)&vT[(hbv + ns * 16 + l15) * NSEQ + ch * 160 + kc * 32 + l4 * 8];
                acc[ns] = __builtin_amdgcn_mfma_f32_16x16x32_bf16(aV, bP, acc[ns], 0, 0, 0);  // wa^T
            }
        }
    }

    // epilogue: wa^T frag (row=d=quad*4+reg, col=q=l15); normalize, * gate, ushort4 stores
    float rn = 1.f / lrun;
    int q = qrow + l15;
    #pragma unroll
    for (int ns = 0; ns < 2; ++ns) {
        int d0 = ns * 16 + l4 * 4;
        ushort4 gv = *(const ushort4*)&gh[(hb + q) * 32 + d0];
        ushort4 o;
        o.x = f2bf(acc[ns][0] * rn * bf2f(gv.x));
        o.y = f2bf(acc[ns][1] * rn * bf2f(gv.y));
        o.z = f2bf(acc[ns][2] * rn * bf2f(gv.z));
        o.w = f2bf(acc[ns][3] * rn * bf2f(gv.w));
        *(ushort4*)&waG[(hb + q) * 32 + d0] = o;
    }
}

// ---------------- k3: output projection ----------------
__global__ __launch_bounds__(256, 3) void out_proj_kernel(
    const unsigned short* __restrict__ waG, const unsigned short* __restrict__ woutb,
    float* __restrict__ out)
{
    __shared__ __align__(16) unsigned short A_lds[64 * 138];
    __shared__ __align__(16) unsigned short B_lds[128 * 138];
    const int tid  = threadIdx.x;
    const int row0 = blockIdx.x * 64;
    const int bidx = row0 / NSEQ;           // 320%64==0
    const int qoff = row0 % NSEQ;

    #pragma unroll
    for (int it = 0; it < 4; ++it) {
        int f = it * 256 + tid;
        int row = f >> 4, c16 = f & 15;
        int hh = c16 >> 2, d0 = (c16 & 3) * 8;
        uint4 u = *(const uint4*)&waG[((size_t)(bidx * 4 + hh) * NSEQ + (qoff + row)) * 32 + d0];
        *(uint4*)&A_lds[row * 138 + c16 * 8] = u;
    }
    #pragma unroll
    for (int it = 0; it < 8; ++it) {
        int f = it * 256 + tid;
        int row = f >> 4, c16 = f & 15;
        uint4 u = *(const uint4*)&woutb[f * 8];
        *(uint4*)&B_lds[row * 138 + c16 * 8] = u;
    }
    __syncthreads();

    const int wave = tid >> 6, lane = tid & 63, l15 = lane & 15, l4 = lane >> 4;
    bf16x8 afrag[4];
    #pragma unroll
    for (int kc = 0; kc < 4; ++kc)
        afrag[kc] = *(const bf16x8*)&A_lds[(wave * 16 + l15) * 138 + kc * 32 + l4 * 8];
    f32x4 acc[8];
    #pragma unroll
    for (int ns = 0; ns < 8; ++ns) { f32x4 z = {0.f,0.f,0.f,0.f}; acc[ns] = z; }
    #pragma unroll
    for (int ns = 0; ns < 8; ++ns)
        #pragma unroll
        for (int kc = 0; kc < 4; ++kc) {
            bf16x8 bfrag = *(const bf16x8*)&B_lds[(ns * 16 + l15) * 138 + kc * 32 + l4 * 8];
            acc[ns] = __builtin_amdgcn_mfma_f32_16x16x32_bf16(afrag[kc], bfrag, acc[ns], 0, 0, 0);
        }
    #pragma unroll
    for (int ns = 0; ns < 8; ++ns)
        #pragma unroll
        for (int reg = 0; reg < 4; ++reg) {
            int r = row0 + wave * 16 + l4 * 4 + reg;
            out[(size_t)r * 128 + ns * 16 + l15] = acc[ns][reg];
        }
}

// ---------------- launch ----------------
extern "C" void kernel_launch(void* const* d_in, const int* in_sizes, int n_in,
                              void* d_out, int out_size, void* d_ws, size_t ws_size,
                              hipStream_t stream)
{
    (void)in_sizes; (void)n_in; (void)out_size;
    const float* act  = (const float*)d_in[0];
    const int*   pmsk = (const int*)d_in[1];
    const float* gam  = (const float*)d_in[2];
    const float* bet  = (const float*)d_in[3];
    const float* wpb  = (const float*)d_in[4];
    const float* wq   = (const float*)d_in[5];
    const float* wk   = (const float*)d_in[6];
    const float* wv   = (const float*)d_in[7];
    const float* wg   = (const float*)d_in[8];
    const float* wo   = (const float*)d_in[9];
    float* out = (float*)d_out;

    char* ws = (char*)d_ws;
    unsigned short* wcat  = (unsigned short*)(ws + 0);          //   147456 B
    unsigned short* woutb = (unsigned short*)(ws + 147456);     //    32768 B
    int*            maskT = (int*)           (ws + 180224);     //   409600 B
    float*          biasS = (float*)         (ws + 589824);     //  1638400 B (S^T swizzled)
    unsigned short* qh    = (unsigned short*)(ws + 2228224);    // 26214400 B
    unsigned short* kh    = (unsigned short*)(ws + 28442624);
    unsigned short* vT    = (unsigned short*)(ws + 54657024);
    unsigned short* gh    = (unsigned short*)(ws + 80871424);
    unsigned short* waG   = (unsigned short*)(ws + 107085824);  // head-major, ends 133300224
    if (ws_size < 133300224ull) {
        fprintf(stderr, "kernel_launch: ws too small (%zu < 133300224)\n", ws_size);
        return;
    }

    prep_kernel    <<<377,  256, 0, stream>>>(wq, wk, wv, wg, wpb, wo, pmsk, wcat, woutb, maskT);
    ln_proj_kernel <<<800,  256, 0, stream>>>(act, gam, bet, wcat, qh, kh, vT, gh, biasS);
    attn_kernel    <<<6400, 256, 0, stream>>>(qh, kh, vT, gh, biasS, maskT, waG);
    out_proj_kernel<<<1600, 256, 0, stream>>>(waG, woutb, out);
}

// Round 6
// 363.719 us; speedup vs baseline: 1.0175x; 1.0175x over previous
//
#include <hip/hip_runtime.h>
#include <cstdio>
#include <cstdint>

// GridSelfAttention: N=320 seq, C=128 ch, H=4 heads, D=32 head-dim.
// k0 prep -> k1 LN+proj GEMM -> k2 attention (R4 skeleton + pk-cvt + deferred
// norm) -> k3 output GEMM. Strides 138/69 kill the 8-way LDS conflicts.

#define NSEQ 320
#define CCH  128
#define NN   102400
#define QK_SCALE 0.17677669529663687f
#define LN_EPS 1e-5f
#define NEG_BIG -1e9f

typedef __bf16 bf16x8 __attribute__((ext_vector_type(8)));
typedef float  f32x4  __attribute__((ext_vector_type(4)));

__device__ __forceinline__ unsigned short f2bf(float f) {
    unsigned int u = __float_as_uint(f);
    unsigned int r = (u + 0x7FFFu + ((u >> 16) & 1u)) >> 16;  // RNE
    return (unsigned short)r;
}
// packed RNE f32x2 -> bf16x2 (1 VALU op on gfx950; safe fallback otherwise)
__device__ __forceinline__ unsigned int f2bf_pk(float a, float b) {
#if __has_builtin(__builtin_amdgcn_cvt_pk_bf16_f32)
    typedef __bf16 bf16x2 __attribute__((ext_vector_type(2)));
    bf16x2 v = __builtin_amdgcn_cvt_pk_bf16_f32(a, b);
    unsigned int u; __builtin_memcpy(&u, &v, 4); return u;
#else
    return (unsigned int)f2bf(a) | ((unsigned int)f2bf(b) << 16);
#endif
}
__device__ __forceinline__ float bf2f(unsigned short h) {
    return __uint_as_float(((unsigned int)h) << 16);
}

// ---------------- k0: weight prep + LDS-tiled mask transpose ----------------
__global__ __launch_bounds__(256) void prep_kernel(
    const float* __restrict__ wq, const float* __restrict__ wk, const float* __restrict__ wv,
    const float* __restrict__ wg, const float* __restrict__ wpb, const float* __restrict__ wo,
    const int* __restrict__ pmask,
    unsigned short* __restrict__ wcat, unsigned short* __restrict__ woutb, int* __restrict__ maskT)
{
    const int tid = threadIdx.x;
    if (blockIdx.x < 352) {
        int idx = blockIdx.x * 256 + tid;
        if (idx < 576 * 128) {
            int n = idx >> 7, c = idx & 127;
            float v;
            if      (n < 128) v = wq[c * 128 + n] * QK_SCALE;
            else if (n < 256) v = wk[c * 128 + (n - 128)];
            else if (n < 384) v = wv[c * 128 + (n - 256)];
            else if (n < 512) v = wg[c * 128 + (n - 384)];
            else if (n < 516) v = wpb[c * 4 + (n - 512)];
            else              v = 0.f;
            wcat[idx] = f2bf(v);
        } else {
            int i = idx - 576 * 128;
            woutb[i] = f2bf(wo[i]);
        }
    } else {
        __shared__ int tile[64][65];
        int tb = blockIdx.x - 352;
        int ti = tb / 5, tj = tb % 5;     // maskT[b][k] = pmask[k][b]
        #pragma unroll
        for (int it = 0; it < 16; ++it) {
            int e = it * 256 + tid;
            int r = e >> 6, c = e & 63;
            tile[r][c] = pmask[(ti * 64 + r) * NSEQ + tj * 64 + c];
        }
        __syncthreads();
        #pragma unroll
        for (int it = 0; it < 16; ++it) {
            int e = it * 256 + tid;
            int r = e >> 6, c = e & 63;
            maskT[(tj * 64 + r) * NSEQ + ti * 64 + c] = tile[c][r];
        }
    }
}

// ---------------- k1: LayerNorm + fused projection GEMM ----------------
// Outputs: qh/kh/gh[(g)*320+pos][32] bf16 (gh sigmoid), vT[(g)*32+d][key] bf16,
// biasS in k2 C-fragment order.
__global__ __launch_bounds__(256, 4) void ln_proj_kernel(
    const float* __restrict__ act, const float* __restrict__ gamma, const float* __restrict__ beta,
    const unsigned short* __restrict__ wcat,
    unsigned short* __restrict__ qh, unsigned short* __restrict__ kh, unsigned short* __restrict__ vT,
    unsigned short* __restrict__ gh, float* __restrict__ biasS)
{
    __shared__ __align__(16) float          fs[64 * 132];            // fp32 act stage, later aliased by B
    __shared__ __align__(16) unsigned short A_lds[64 * 138];         // LN bf16; later fp32 scratch 64x69
    unsigned short* B_lds = (unsigned short*)fs;                     // alias (33792 B >= 17664 B)

    const int tid  = threadIdx.x;
    const int row0 = blockIdx.x * 64;
    const int bidx = row0 / NSEQ;           // 320%64==0 -> tile never crosses b
    const int qoff = row0 % NSEQ;

    const float4* actv = (const float4*)(act + (size_t)row0 * 128);
    #pragma unroll
    for (int it = 0; it < 8; ++it) {
        int f = it * 256 + tid;
        int row = f >> 5, c4 = f & 31;
        float4 v = actv[f];
        *(float4*)&fs[row * 132 + c4 * 4] = v;
    }
    __syncthreads();

    {
        int row = tid >> 2, seg = tid & 3;
        const float* rp = &fs[row * 132 + seg * 32];
        float vals[32];
        float s = 0.f, sq = 0.f;
        #pragma unroll
        for (int i = 0; i < 32; ++i) { float v = rp[i]; vals[i] = v; s += v; sq += v * v; }
        s  += __shfl_xor(s, 1);  sq += __shfl_xor(sq, 1);
        s  += __shfl_xor(s, 2);  sq += __shfl_xor(sq, 2);
        float mean = s * (1.f / 128.f);
        float var  = sq * (1.f / 128.f) - mean * mean;
        float rstd = rsqrtf(var + LN_EPS);
        #pragma unroll
        for (int j = 0; j < 4; ++j) {
            int c0 = seg * 32 + j * 8;
            float4 g0 = *(const float4*)&gamma[c0];
            float4 g1 = *(const float4*)&gamma[c0 + 4];
            float4 b0 = *(const float4*)&beta[c0];
            float4 b1 = *(const float4*)&beta[c0 + 4];
            union { uint4 u; unsigned int w[4]; } pk;
            pk.w[0] = f2bf_pk((vals[j*8+0]-mean)*rstd*g0.x+b0.x, (vals[j*8+1]-mean)*rstd*g0.y+b0.y);
            pk.w[1] = f2bf_pk((vals[j*8+2]-mean)*rstd*g0.z+b0.z, (vals[j*8+3]-mean)*rstd*g0.w+b0.w);
            pk.w[2] = f2bf_pk((vals[j*8+4]-mean)*rstd*g1.x+b1.x, (vals[j*8+5]-mean)*rstd*g1.y+b1.y);
            pk.w[3] = f2bf_pk((vals[j*8+6]-mean)*rstd*g1.z+b1.z, (vals[j*8+7]-mean)*rstd*g1.w+b1.w);
            *(uint4*)&A_lds[row * 138 + c0] = pk.u;
        }
    }
    __syncthreads();

    const int wave = tid >> 6, lane = tid & 63, l15 = lane & 15, l4 = lane >> 4;
    bf16x8 afrag[4];
    #pragma unroll
    for (int kc = 0; kc < 4; ++kc)
        afrag[kc] = *(const bf16x8*)&A_lds[(wave * 16 + l15) * 138 + kc * 32 + l4 * 8];

    float* scratch = (float*)A_lds;   // 64 x 69 fp32 = 17664 B, exact fit

    for (int nt = 0; nt < 9; ++nt) {
        #pragma unroll
        for (int it = 0; it < 4; ++it) {
            int f = it * 256 + tid;
            int row = f >> 4, c16 = f & 15;
            uint4 u = *(const uint4*)&wcat[(nt * 64 + row) * 128 + c16 * 8];
            *(uint4*)&B_lds[row * 138 + c16 * 8] = u;
        }
        __syncthreads();

        f32x4 acc[4];
        #pragma unroll
        for (int ns = 0; ns < 4; ++ns) { f32x4 z = {0.f,0.f,0.f,0.f}; acc[ns] = z; }
        #pragma unroll
        for (int ns = 0; ns < 4; ++ns)
            #pragma unroll
            for (int kc = 0; kc < 4; ++kc) {
                bf16x8 bfrag = *(const bf16x8*)&B_lds[(ns * 16 + l15) * 138 + kc * 32 + l4 * 8];
                acc[ns] = __builtin_amdgcn_mfma_f32_16x16x32_bf16(afrag[kc], bfrag, acc[ns], 0, 0, 0);
            }

        if (nt == 4 || nt == 5) {
            // V -> vT direct from C-frags (4 consecutive keys per lane)
            int key0 = qoff + wave * 16 + l4 * 4;
            #pragma unroll
            for (int ns = 0; ns < 4; ++ns) {
                int j  = nt * 64 + ns * 16 + l15 - 256;   // 0..255
                int hh = j >> 5, d = j & 31;
                uint2 pk;
                pk.x = f2bf_pk(acc[ns][0], acc[ns][1]);
                pk.y = f2bf_pk(acc[ns][2], acc[ns][3]);
                *(uint2*)&vT[((size_t)(bidx * 4 + hh) * 32 + d) * NSEQ + key0] = pk;
            }
            __syncthreads();   // protect B_lds before next staging
        } else if (nt == 8) {
            // bias -> k2 C-fragment order
            #pragma unroll
            for (int ns = 0; ns < 4; ++ns) {
                int j = nt * 64 + ns * 16 + l15;
                if (j < 516) {
                    #pragma unroll
                    for (int reg = 0; reg < 4; ++reg) {
                        int r  = row0 + wave * 16 + l4 * 4 + reg;
                        int hh = j - 512;
                        int q  = r / NSEQ, key = r - q * NSEQ;
                        int qm = q & 15,  kl  = key & 15;
                        size_t a = (((size_t)(hh * 20 + (q >> 4)) * 20 + (key >> 4)) << 8)
                                 + ((qm >> 2) << 6) + (kl << 2) + (qm & 3);
                        biasS[a] = acc[ns][reg];
                    }
                }
            }
        } else {
            // q / k / gate: transpose C-frags via fp32 scratch (stride 69: conflict-free)
            #pragma unroll
            for (int ns = 0; ns < 4; ++ns)
                #pragma unroll
                for (int reg = 0; reg < 4; ++reg)
                    scratch[(wave * 16 + l4 * 4 + reg) * 69 + ns * 16 + l15] = acc[ns][reg];
            __syncthreads();

            int rrow = tid >> 2, c16 = tid & 3;
            int q = qoff + rrow;
            float f[16];
            #pragma unroll
            for (int i = 0; i < 4; ++i)
                *(float4*)&f[i * 4] = *(const float4*)&scratch[rrow * 69 + c16 * 16 + i * 4];

            int jbase = nt * 64 + c16 * 16;
            int cls   = jbase >> 7;            // 0=q, 1=k, 3=gate
            int jl    = jbase & 127;
            int hh = jl >> 5, d0 = jl & 31;
            unsigned short* dst = (cls == 0) ? qh : (cls == 1) ? kh : gh;
            if (cls == 3) {
                #pragma unroll
                for (int i = 0; i < 16; ++i) f[i] = 1.f / (1.f + __expf(-f[i]));
            }
            union { uint4 u[2]; unsigned int w[8]; } pk;
            #pragma unroll
            for (int i = 0; i < 8; ++i) pk.w[i] = f2bf_pk(f[2*i], f[2*i+1]);
            size_t base = ((size_t)(bidx * 4 + hh) * NSEQ + q) * 32 + d0;
            *(uint4*)&dst[base]     = pk.u[0];
            *(uint4*)&dst[base + 8] = pk.u[1];
        }
    }
}

// ---------------- k2: attention ----------------
// R4 skeleton: block=(b,h,q64) XCD-swizzled; K in LDS (stride 36); bias preloaded
// as MFMA C; single-pass softmax; P streamed via per-wave LDS dbuf; head-major out.
// New: packed bf16 converts, normalization deferred to epilogue.
__global__ __launch_bounds__(256, 4) void attn_kernel(
    const unsigned short* __restrict__ qh, const unsigned short* __restrict__ kh,
    const unsigned short* __restrict__ vT, const unsigned short* __restrict__ gh,
    const float* __restrict__ biasS, const int* __restrict__ maskT,
    unsigned short* __restrict__ waG)
{
    __shared__ __align__(16) unsigned short Klds[320 * 36];     // 23040 B
    __shared__ __align__(16) unsigned short Pb[4][2][16 * 36];  //  9216 B

    const int tid  = threadIdx.x;
    const int bid  = blockIdx.x;
    const int xcd  = bid & 7;
    const int loc  = bid >> 3;
    const int qblk = loc % 5;
    const int g    = (loc / 5) * 8 + xcd;    // (b,h); 5 qblk siblings share an XCD L2
    const int b    = g >> 2;
    const int h    = g & 3;
    const int wave = tid >> 6, lane = tid & 63, l15 = lane & 15, l4 = lane >> 4;

    const size_t hb  = (size_t)g * NSEQ;
    const size_t hbv = (size_t)g * 32;

    // cooperative K staging [key][d], stride 36
    {
        const uint4* src = (const uint4*)(kh + hb * 32);
        #pragma unroll
        for (int it = 0; it < 5; ++it) {
            int idx = it * 256 + tid;
            int key = idx >> 2, part = idx & 3;
            uint4 u = src[idx];
            *(uint4*)&Klds[key * 36 + part * 8] = u;
        }
    }

    const int qrow = qblk * 64 + wave * 16;
    const int qb16 = qblk * 4 + wave;

    bf16x8 aQ = *(const bf16x8*)&qh[(hb + qrow + l15) * 32 + l4 * 8];
    const float* bsw = biasS + (size_t)(h * 20 + qb16) * 20 * 256 + lane * 4;
    const int*   mp  = maskT + b * NSEQ + l15;

    // all 20 bias C-operands issued together
    f32x4 s[20];
    #pragma unroll
    for (int t = 0; t < 20; ++t) s[t] = *(const f32x4*)&bsw[t * 256];

    __syncthreads();

    // S = Q K^T + bias
    #pragma unroll
    for (int t = 0; t < 20; ++t) {
        bf16x8 bK = *(const bf16x8*)&Klds[(t * 16 + l15) * 36 + l4 * 8];
        s[t] = __builtin_amdgcn_mfma_f32_16x16x32_bf16(aQ, bK, s[t], 0, 0, 0);
    }

    // mask (key,b) -> exactly -1e9
    #pragma unroll
    for (int t = 0; t < 20; ++t) {
        int m = mp[t * 16];
        #pragma unroll
        for (int r = 0; r < 4; ++r) s[t][r] = m ? s[t][r] : NEG_BIG;
    }

    // softmax (unnormalized): keep 1/l for epilogue
    float rn[4];
    #pragma unroll
    for (int r = 0; r < 4; ++r) {
        float mx = -3.4e38f;
        #pragma unroll
        for (int t = 0; t < 20; ++t) mx = fmaxf(mx, s[t][r]);
        mx = fmaxf(mx, __shfl_xor(mx, 1));
        mx = fmaxf(mx, __shfl_xor(mx, 2));
        mx = fmaxf(mx, __shfl_xor(mx, 4));
        mx = fmaxf(mx, __shfl_xor(mx, 8));
        float l = 0.f;
        #pragma unroll
        for (int t = 0; t < 20; ++t) { float p = __expf(s[t][r] - mx); s[t][r] = p; l += p; }
        l += __shfl_xor(l, 1); l += __shfl_xor(l, 2); l += __shfl_xor(l, 4); l += __shfl_xor(l, 8);
        rn[r] = 1.f / l;
    }

    // PV: P streamed through per-wave LDS dbuf (32 keys/chunk); packed converts
    unsigned short* pb[2] = { Pb[wave][0], Pb[wave][1] };
    #pragma unroll
    for (int tt = 0; tt < 2; ++tt) {
        unsigned int u01 = f2bf_pk(s[tt][0], s[tt][1]);
        unsigned int u23 = f2bf_pk(s[tt][2], s[tt][3]);
        unsigned short* c = &pb[0][(l4 * 4) * 36 + tt * 16 + l15];
        c[0]   = (unsigned short)(u01 & 0xffff);
        c[36]  = (unsigned short)(u01 >> 16);
        c[72]  = (unsigned short)(u23 & 0xffff);
        c[108] = (unsigned short)(u23 >> 16);
    }

    f32x4 acc[2];
    { f32x4 z = {0.f,0.f,0.f,0.f}; acc[0] = z; acc[1] = z; }
    #pragma unroll
    for (int kc = 0; kc < 10; ++kc) {
        bf16x8 aW = *(const bf16x8*)&pb[kc & 1][l15 * 36 + l4 * 8];
        if (kc < 9) {
            unsigned short* nxt = pb[(kc + 1) & 1];
            #pragma unroll
            for (int tt = 0; tt < 2; ++tt) {
                unsigned int u01 = f2bf_pk(s[2*kc+2+tt][0], s[2*kc+2+tt][1]);
                unsigned int u23 = f2bf_pk(s[2*kc+2+tt][2], s[2*kc+2+tt][3]);
                unsigned short* c = &nxt[(l4 * 4) * 36 + tt * 16 + l15];
                c[0]   = (unsigned short)(u01 & 0xffff);
                c[36]  = (unsigned short)(u01 >> 16);
                c[72]  = (unsigned short)(u23 & 0xffff);
                c[108] = (unsigned short)(u23 >> 16);
            }
        }
        #pragma unroll
        for (int ns = 0; ns < 2; ++ns) {
            bf16x8 bV = *(const bf16x8*)&vT[(hbv + ns * 16 + l15) * NSEQ + kc * 32 + l4 * 8];
            acc[ns] = __builtin_amdgcn_mfma_f32_16x16x32_bf16(aW, bV, acc[ns], 0, 0, 0);
        }
    }

    // epilogue: normalize (deferred), * gate -> bf16, head-major
    #pragma unroll
    for (int ns = 0; ns < 2; ++ns)
        #pragma unroll
        for (int r = 0; r < 4; ++r) {
            int q   = qrow + l4 * 4 + r;
            int col = ns * 16 + l15;
            float gv = bf2f(gh[(hb + q) * 32 + col]);
            waG[(hb + q) * 32 + col] = f2bf(acc[ns][r] * rn[r] * gv);
        }
}

// ---------------- k3: output projection ----------------
__global__ __launch_bounds__(256, 3) void out_proj_kernel(
    const unsigned short* __restrict__ waG, const unsigned short* __restrict__ woutb,
    float* __restrict__ out)
{
    __shared__ __align__(16) unsigned short A_lds[64 * 138];
    __shared__ __align__(16) unsigned short B_lds[128 * 138];
    const int tid  = threadIdx.x;
    const int row0 = blockIdx.x * 64;
    const int bidx = row0 / NSEQ;           // 320%64==0
    const int qoff = row0 % NSEQ;

    #pragma unroll
    for (int it = 0; it < 4; ++it) {
        int f = it * 256 + tid;
        int row = f >> 4, c16 = f & 15;
        int hh = c16 >> 2, d0 = (c16 & 3) * 8;
        uint4 u = *(const uint4*)&waG[((size_t)(bidx * 4 + hh) * NSEQ + (qoff + row)) * 32 + d0];
        *(uint4*)&A_lds[row * 138 + c16 * 8] = u;
    }
    #pragma unroll
    for (int it = 0; it < 8; ++it) {
        int f = it * 256 + tid;
        int row = f >> 4, c16 = f & 15;
        uint4 u = *(const uint4*)&woutb[f * 8];
        *(uint4*)&B_lds[row * 138 + c16 * 8] = u;
    }
    __syncthreads();

    const int wave = tid >> 6, lane = tid & 63, l15 = lane & 15, l4 = lane >> 4;
    bf16x8 afrag[4];
    #pragma unroll
    for (int kc = 0; kc < 4; ++kc)
        afrag[kc] = *(const bf16x8*)&A_lds[(wave * 16 + l15) * 138 + kc * 32 + l4 * 8];
    f32x4 acc[8];
    #pragma unroll
    for (int ns = 0; ns < 8; ++ns) { f32x4 z = {0.f,0.f,0.f,0.f}; acc[ns] = z; }
    #pragma unroll
    for (int ns = 0; ns < 8; ++ns)
        #pragma unroll
        for (int kc = 0; kc < 4; ++kc) {
            bf16x8 bfrag = *(const bf16x8*)&B_lds[(ns * 16 + l15) * 138 + kc * 32 + l4 * 8];
            acc[ns] = __builtin_amdgcn_mfma_f32_16x16x32_bf16(afrag[kc], bfrag, acc[ns], 0, 0, 0);
        }
    #pragma unroll
    for (int ns = 0; ns < 8; ++ns)
        #pragma unroll
        for (int reg = 0; reg < 4; ++reg) {
            int r = row0 + wave * 16 + l4 * 4 + reg;
            out[(size_t)r * 128 + ns * 16 + l15] = acc[ns][reg];
        }
}

// ---------------- launch ----------------
extern "C" void kernel_launch(void* const* d_in, const int* in_sizes, int n_in,
                              void* d_out, int out_size, void* d_ws, size_t ws_size,
                              hipStream_t stream)
{
    (void)in_sizes; (void)n_in; (void)out_size;
    const float* act  = (const float*)d_in[0];
    const int*   pmsk = (const int*)d_in[1];
    const float* gam  = (const float*)d_in[2];
    const float* bet  = (const float*)d_in[3];
    const float* wpb  = (const float*)d_in[4];
    const float* wq   = (const float*)d_in[5];
    const float* wk   = (const float*)d_in[6];
    const float* wv   = (const float*)d_in[7];
    const float* wg   = (const float*)d_in[8];
    const float* wo   = (const float*)d_in[9];
    float* out = (float*)d_out;

    char* ws = (char*)d_ws;
    unsigned short* wcat  = (unsigned short*)(ws + 0);          //   147456 B
    unsigned short* woutb = (unsigned short*)(ws + 147456);     //    32768 B
    int*            maskT = (int*)           (ws + 180224);     //   409600 B
    float*          biasS = (float*)         (ws + 589824);     //  1638400 B (swizzled)
    unsigned short* qh    = (unsigned short*)(ws + 2228224);    // 26214400 B
    unsigned short* kh    = (unsigned short*)(ws + 28442624);
    unsigned short* vT    = (unsigned short*)(ws + 54657024);
    unsigned short* gh    = (unsigned short*)(ws + 80871424);
    unsigned short* waG   = (unsigned short*)(ws + 107085824);  // head-major, ends 133300224
    if (ws_size < 133300224ull) {
        fprintf(stderr, "kernel_launch: ws too small (%zu < 133300224)\n", ws_size);
        return;
    }

    prep_kernel    <<<377,  256, 0, stream>>>(wq, wk, wv, wg, wpb, wo, pmsk, wcat, woutb, maskT);
    ln_proj_kernel <<<1600, 256, 0, stream>>>(act, gam, bet, wcat, qh, kh, vT, gh, biasS);
    attn_kernel    <<<6400, 256, 0, stream>>>(qh, kh, vT, gh, biasS, maskT, waG);
    out_proj_kernel<<<1600, 256, 0, stream>>>(waG, woutb, out);
}